// Round 5
// baseline (643.659 us; speedup 1.0000x reference)
//
#include <hip/hip_runtime.h>

#define NN 50000
#define NE 1600000
#define DD 128
#define NL 4
#define NG 512
#define NT 196      // ceil(NN/256)
#define NREP 8      // degree-counter replicas (one per XCD via blockIdx&7)
#define RSTRIDE 50176  // NT*256, padded node stride for replica arrays
#define NBE 1563    // ceil(NE/4/256)

typedef __attribute__((ext_vector_type(8))) short short8;
typedef __attribute__((ext_vector_type(4))) float floatx4;

__device__ __forceinline__ unsigned short f2bf(float f) {
    unsigned int u = __float_as_uint(f);
    u += 0x7fffu + ((u >> 16) & 1u);
    return (unsigned short)(u >> 16);
}
__device__ __forceinline__ float bf2f(unsigned short u) {
    return __uint_as_float(((unsigned int)u) << 16);
}

// ---------- fp32 -> bf16 convert (layer-0 input) ----------
__global__ __launch_bounds__(256) void cvt_kernel(const float* __restrict__ x,
                                                  unsigned short* __restrict__ xbf) {
    int idx = blockIdx.x * 256 + threadIdx.x;  // one float4 per thread
    float4 f = ((const float4*)x)[idx];
    ushort4 o;
    o.x = f2bf(f.x); o.y = f2bf(f.y); o.z = f2bf(f.z); o.w = f2bf(f.w);
    ((ushort4*)xbf)[idx] = o;
}

// ---------- CSR build ----------
// pos_kernel: atomic pass over replicated counters; returns per-edge slot within
// (replica, node). rep = blockIdx&7 keeps each replica's lines on ~one XCD's L2,
// killing the cross-XCD line ping-pong (was 56 MB WRITE_SIZE for 8 MB payload).
__global__ __launch_bounds__(256) void pos_kernel(const int* __restrict__ dst,
                                                  int* __restrict__ degr,
                                                  int* __restrict__ pos) {
    int t = blockIdx.x * 256 + threadIdx.x;  // [0, NE/4)
    if (t >= NE / 4) return;
    int* d0 = degr + (blockIdx.x & (NREP - 1)) * RSTRIDE;
    int4 d = ((const int4*)dst)[t];
    int4 p;
    p.x = atomicAdd(&d0[d.x], 1);
    p.y = atomicAdd(&d0[d.y], 1);
    p.z = atomicAdd(&d0[d.z], 1);
    p.w = atomicAdd(&d0[d.w], 1);
    ((int4*)pos)[t] = p;
}

// merge: per node, exclusive prefix over the 8 replica counts (in place -> roff),
// total -> deg
__global__ __launch_bounds__(256) void merge_kernel(int* __restrict__ degr,
                                                    int* __restrict__ deg) {
    int i = blockIdx.x * 256 + threadIdx.x;
    if (i >= NN) return;
    int s = 0;
#pragma unroll
    for (int r = 0; r < NREP; r++) {
        int t = degr[r * RSTRIDE + i];
        degr[r * RSTRIDE + i] = s;
        s += t;
    }
    deg[i] = s;
}

// ---------- parallel exclusive scan of deg -> rowptr (3 kernels, full-chip) ----------
__global__ __launch_bounds__(256) void tilesum_kernel(const int* __restrict__ deg,
                                                      int* __restrict__ tilesum) {
    int i = blockIdx.x * 256 + threadIdx.x;
    int v = (i < NN) ? deg[i] : 0;
    __shared__ int s[256];
    s[threadIdx.x] = v;
    __syncthreads();
    for (int off = 128; off > 0; off >>= 1) {
        if (threadIdx.x < off) s[threadIdx.x] += s[threadIdx.x + off];
        __syncthreads();
    }
    if (threadIdx.x == 0) tilesum[blockIdx.x] = s[0];
}

__global__ __launch_bounds__(256) void tilescan_kernel(const int* __restrict__ tilesum,
                                                       int* __restrict__ tileoff,
                                                       int* __restrict__ rowptr) {
    int t = threadIdx.x;
    __shared__ int s[256];
    int v = (t < NT) ? tilesum[t] : 0;
    s[t] = v;
    __syncthreads();
    for (int off = 1; off < 256; off <<= 1) {
        int u = (t >= off) ? s[t - off] : 0;
        __syncthreads();
        s[t] += u;
        __syncthreads();
    }
    if (t < NT) tileoff[t] = s[t] - v;   // exclusive tile offset
    if (t == NT - 1) rowptr[NN] = s[t];  // grand total
}

__global__ __launch_bounds__(256) void rowptr_kernel(const int* __restrict__ deg,
                                                     const int* __restrict__ tileoff,
                                                     int* __restrict__ rowptr) {
    int i = blockIdx.x * 256 + threadIdx.x;
    int t = threadIdx.x;
    int v = (i < NN) ? deg[i] : 0;
    __shared__ int s[256];
    s[t] = v;
    __syncthreads();
    for (int off = 1; off < 256; off <<= 1) {
        int u = (t >= off) ? s[t - off] : 0;
        __syncthreads();
        s[t] += u;
        __syncthreads();
    }
    if (i < NN) rowptr[i] = tileoff[blockIdx.x] + s[t] - v;
}

// atomic-free scatter: col[rowptr[d] + roff[rep][d] + pos[e]] = src[e]
__global__ __launch_bounds__(256) void fill_kernel(const int* __restrict__ src,
                                                   const int* __restrict__ dst,
                                                   const int* __restrict__ pos,
                                                   const int* __restrict__ rowptr,
                                                   const int* __restrict__ roff,
                                                   int* __restrict__ col) {
    int t = blockIdx.x * 256 + threadIdx.x;  // [0, NE/4)
    if (t >= NE / 4) return;
    const int* ro = roff + (blockIdx.x & (NREP - 1)) * RSTRIDE;
    int4 d = ((const int4*)dst)[t];
    int4 p = ((const int4*)pos)[t];
    int4 s = ((const int4*)src)[t];
    col[rowptr[d.x] + ro[d.x] + p.x] = s.x;
    col[rowptr[d.y] + ro[d.y] + p.y] = s.y;
    col[rowptr[d.z] + ro[d.z] + p.z] = s.z;
    col[rowptr[d.w] + ro[d.w] + p.w] = s.w;
}

// ---------- weight prep: fp32 [l][k][n] -> bf16 transposed [l][n][k] ----------
__global__ __launch_bounds__(256) void prep_kernel(const float* __restrict__ Ws1,
                                                   const float* __restrict__ Ws2,
                                                   unsigned short* __restrict__ W1T,
                                                   unsigned short* __restrict__ W2T) {
    int idx = blockIdx.x * 256 + threadIdx.x;  // [0, NL*DD*DD)
    int l = idx >> 14;
    int rem = idx & 16383;
    int k = rem >> 7;
    int n = rem & 127;
    int o = (l << 14) + (n << 7) + k;
    W1T[o] = f2bf(Ws1[idx]);
    W2T[o] = f2bf(Ws2[idx]);
}

// ---------- fused GIN layer: agg (gather-sum) -> LDS -> relu(·W1+b1)·W2+b2 ----------
// 64 nodes/block. Phase 1: 32 lanes/node, 8 nodes per pass, fp32 accum -> Hs (bf16).
// Phase 2/3: per-wave 16-row slice; each wave reads/writes ONLY its own rows, so a
// single barrier after phase 1 suffices (extra barriers kept for safety, cost ~0).
__global__ __launch_bounds__(256) void gin_layer_kernel(
    const unsigned short* __restrict__ xbf,
    const int* __restrict__ rowptr,
    const int* __restrict__ col,
    const unsigned short* __restrict__ W1T,
    const float* __restrict__ b1,
    const unsigned short* __restrict__ W2T,
    const float* __restrict__ b2,
    unsigned short* __restrict__ out) {
    __shared__ unsigned short Hs[64][136];  // +8 pad
    int tid = threadIdx.x;
    int row0 = blockIdx.x * 64;

    // ---- phase 1: aggregation into Hs ----
    {
        int g = tid >> 5;
        int lane = tid & 31;
        int co = lane * 4;
        for (int nn = 0; nn < 8; nn++) {
            int r = nn * 8 + g;
            int node = row0 + r;
            float a0 = 0.f, a1 = 0.f, a2 = 0.f, a3 = 0.f;
            if (node < NN) {
                ushort4 v = *(const ushort4*)(xbf + (size_t)node * DD + co);
                a0 = bf2f(v.x); a1 = bf2f(v.y); a2 = bf2f(v.z); a3 = bf2f(v.w);
                int s = rowptr[node], e = rowptr[node + 1];
                int i = s;
                for (; i + 4 <= e; i += 4) {
                    int j0 = col[i], j1 = col[i + 1], j2 = col[i + 2], j3 = col[i + 3];
                    ushort4 v0 = *(const ushort4*)(xbf + (size_t)j0 * DD + co);
                    ushort4 v1 = *(const ushort4*)(xbf + (size_t)j1 * DD + co);
                    ushort4 v2 = *(const ushort4*)(xbf + (size_t)j2 * DD + co);
                    ushort4 v3 = *(const ushort4*)(xbf + (size_t)j3 * DD + co);
                    a0 += bf2f(v0.x) + bf2f(v1.x) + bf2f(v2.x) + bf2f(v3.x);
                    a1 += bf2f(v0.y) + bf2f(v1.y) + bf2f(v2.y) + bf2f(v3.y);
                    a2 += bf2f(v0.z) + bf2f(v1.z) + bf2f(v2.z) + bf2f(v3.z);
                    a3 += bf2f(v0.w) + bf2f(v1.w) + bf2f(v2.w) + bf2f(v3.w);
                }
                for (; i < e; i++) {
                    int j = col[i];
                    ushort4 v = *(const ushort4*)(xbf + (size_t)j * DD + co);
                    a0 += bf2f(v.x); a1 += bf2f(v.y); a2 += bf2f(v.z); a3 += bf2f(v.w);
                }
            }
            ushort4 o;
            o.x = f2bf(a0); o.y = f2bf(a1); o.z = f2bf(a2); o.w = f2bf(a3);
            *(ushort4*)&Hs[r][co] = o;
        }
    }
    __syncthreads();

    // ---- phase 2/3: MLP ----
    int w = tid >> 6;
    int lane = tid & 63;
    int quad = lane >> 4;
    int li = lane & 15;

    floatx4 acc[8];
#pragma unroll
    for (int tn = 0; tn < 8; tn++) acc[tn] = (floatx4){0.f, 0.f, 0.f, 0.f};

#pragma unroll
    for (int kk = 0; kk < 4; kk++) {
        int k0 = kk * 32 + quad * 8;
        short8 af = *(const short8*)&Hs[16 * w + li][k0];
#pragma unroll
        for (int tn = 0; tn < 8; tn++) {
            short8 bf = *(const short8*)(W1T + ((tn * 16 + li) << 7) + k0);
            acc[tn] = __builtin_amdgcn_mfma_f32_16x16x32_bf16(af, bf, acc[tn], 0, 0, 0);
        }
    }
    __syncthreads();
    // epilogue A: relu(acc + b1) -> Hs (overwrite own 16-row slice)
#pragma unroll
    for (int tn = 0; tn < 8; tn++) {
        float bias = b1[tn * 16 + li];
#pragma unroll
        for (int r = 0; r < 4; r++) {
            float v = acc[tn][r] + bias;
            v = fmaxf(v, 0.f);
            Hs[16 * w + quad * 4 + r][tn * 16 + li] = f2bf(v);
        }
    }
    __syncthreads();

#pragma unroll
    for (int tn = 0; tn < 8; tn++) acc[tn] = (floatx4){0.f, 0.f, 0.f, 0.f};
#pragma unroll
    for (int kk = 0; kk < 4; kk++) {
        int k0 = kk * 32 + quad * 8;
        short8 af = *(const short8*)&Hs[16 * w + li][k0];
#pragma unroll
        for (int tn = 0; tn < 8; tn++) {
            short8 bf = *(const short8*)(W2T + ((tn * 16 + li) << 7) + k0);
            acc[tn] = __builtin_amdgcn_mfma_f32_16x16x32_bf16(af, bf, acc[tn], 0, 0, 0);
        }
    }
#pragma unroll
    for (int tn = 0; tn < 8; tn++) {
        float bias = b2[tn * 16 + li];
#pragma unroll
        for (int r = 0; r < 4; r++) {
            int grow = row0 + 16 * w + quad * 4 + r;
            if (grow < NN) out[(size_t)grow * DD + tn * 16 + li] = f2bf(acc[tn][r] + bias);
        }
    }
}

// ---------- global add pool: batch sorted -> per-graph contiguous range ----------
__global__ __launch_bounds__(128) void pool_kernel(const unsigned short* __restrict__ x,
                                                   const int* __restrict__ batch,
                                                   float* __restrict__ out) {
    int g = blockIdx.x;
    int lo = 0, hi = NN;
    while (lo < hi) { int mid = (lo + hi) >> 1; if (batch[mid] < g) lo = mid + 1; else hi = mid; }
    int s = lo;
    hi = NN;
    while (lo < hi) { int mid = (lo + hi) >> 1; if (batch[mid] < g + 1) lo = mid + 1; else hi = mid; }
    int e = lo;
    int d = threadIdx.x;
    float acc = 0.f;
    for (int i = s; i < e; i++) acc += bf2f(x[(size_t)i * DD + d]);
    out[g * DD + d] = acc;
}

extern "C" void kernel_launch(void* const* d_in, const int* in_sizes, int n_in,
                              void* d_out, int out_size, void* d_ws, size_t ws_size,
                              hipStream_t stream) {
    const float* x0 = (const float*)d_in[0];
    const int* edge = (const int*)d_in[1];
    const int* batch = (const int*)d_in[2];
    const float* Ws1 = (const float*)d_in[3];
    const float* bs1 = (const float*)d_in[4];
    const float* Ws2 = (const float*)d_in[5];
    const float* bs2 = (const float*)d_in[6];
    float* out = (float*)d_out;
    const int* src = edge;
    const int* dst = edge + NE;

    char* ws = (char*)d_ws;
    size_t off = 0;
    auto alloc = [&](size_t bytes) {
        void* p = ws + off;
        off += (bytes + 255) & ~(size_t)255;
        return p;
    };
    unsigned short* x0bf = (unsigned short*)alloc((size_t)NN * DD * 2);
    unsigned short* xA = (unsigned short*)alloc((size_t)NN * DD * 2);
    unsigned short* xB = (unsigned short*)alloc((size_t)NN * DD * 2);
    int* col = (int*)alloc((size_t)NE * 4);
    int* pos = (int*)alloc((size_t)NE * 4);
    int* rowptr = (int*)alloc((size_t)(NN + 1) * 4);
    int* deg = (int*)alloc((size_t)(NN + 1) * 4);
    int* degr = (int*)alloc((size_t)NREP * RSTRIDE * 4);  // counters, then roff in-place
    int* tilesum = (int*)alloc((size_t)NT * 4);
    int* tileoff = (int*)alloc((size_t)NT * 4);
    unsigned short* W1T = (unsigned short*)alloc((size_t)NL * DD * DD * 2);
    unsigned short* W2T = (unsigned short*)alloc((size_t)NL * DD * DD * 2);

    hipMemsetAsync(degr, 0, (size_t)NREP * RSTRIDE * 4, stream);

    cvt_kernel<<<(NN * DD / 4) / 256, 256, 0, stream>>>(x0, x0bf);
    pos_kernel<<<NBE, 256, 0, stream>>>(dst, degr, pos);
    merge_kernel<<<NT, 256, 0, stream>>>(degr, deg);
    tilesum_kernel<<<NT, 256, 0, stream>>>(deg, tilesum);
    tilescan_kernel<<<1, 256, 0, stream>>>(tilesum, tileoff, rowptr);
    rowptr_kernel<<<NT, 256, 0, stream>>>(deg, tileoff, rowptr);
    fill_kernel<<<NBE, 256, 0, stream>>>(src, dst, pos, rowptr, degr, col);
    prep_kernel<<<(NL * DD * DD) / 256, 256, 0, stream>>>(Ws1, Ws2, W1T, W2T);

    const unsigned short* xin = x0bf;
    unsigned short* bufs[2] = {xA, xB};
    for (int l = 0; l < NL; l++) {
        unsigned short* xout = bufs[l & 1];
        gin_layer_kernel<<<(NN + 63) / 64, 256, 0, stream>>>(
            xin, rowptr, col, W1T + l * DD * DD, bs1 + l * DD,
            W2T + l * DD * DD, bs2 + l * DD, xout);
        xin = xout;
    }
    pool_kernel<<<NG, 128, 0, stream>>>(xin, batch, out);
}

// Round 6
// 578.786 us; speedup vs baseline: 1.1121x; 1.1121x over previous
//
#include <hip/hip_runtime.h>

#define NN 50000
#define NE 1600000
#define DD 128
#define NL 4
#define NG 512
#define NT 196      // ceil(NN/256)
#define NREP 8      // degree-counter replicas (one per XCD via blockIdx&7)
#define RSTRIDE 50176  // NT*256, padded node stride for replica arrays
#define NBE 1563    // ceil(NE/4/256)

typedef __attribute__((ext_vector_type(8))) short short8;
typedef __attribute__((ext_vector_type(4))) float floatx4;

__device__ __forceinline__ unsigned short f2bf(float f) {
    unsigned int u = __float_as_uint(f);
    u += 0x7fffu + ((u >> 16) & 1u);
    return (unsigned short)(u >> 16);
}
__device__ __forceinline__ float bf2f(unsigned short u) {
    return __uint_as_float(((unsigned int)u) << 16);
}

// ---------- fp32 -> bf16 convert (layer-0 input) ----------
__global__ __launch_bounds__(256) void cvt_kernel(const float* __restrict__ x,
                                                  unsigned short* __restrict__ xbf) {
    int idx = blockIdx.x * 256 + threadIdx.x;  // one float4 per thread
    float4 f = ((const float4*)x)[idx];
    ushort4 o;
    o.x = f2bf(f.x); o.y = f2bf(f.y); o.z = f2bf(f.z); o.w = f2bf(f.w);
    ((ushort4*)xbf)[idx] = o;
}

// ---------- CSR build ----------
// pos_kernel: atomic pass over replicated counters; rep = blockIdx&7 keeps each
// replica's lines on ~one XCD's L2 (fixed 56 MB -> ~10 MB write amplification).
__global__ __launch_bounds__(256) void pos_kernel(const int* __restrict__ dst,
                                                  int* __restrict__ degr,
                                                  int* __restrict__ pos) {
    int t = blockIdx.x * 256 + threadIdx.x;  // [0, NE/4)
    if (t >= NE / 4) return;
    int* d0 = degr + (blockIdx.x & (NREP - 1)) * RSTRIDE;
    int4 d = ((const int4*)dst)[t];
    int4 p;
    p.x = atomicAdd(&d0[d.x], 1);
    p.y = atomicAdd(&d0[d.y], 1);
    p.z = atomicAdd(&d0[d.z], 1);
    p.w = atomicAdd(&d0[d.w], 1);
    ((int4*)pos)[t] = p;
}

// merge: per node, exclusive prefix over the 8 replica counts (in place -> roff),
// total -> deg
__global__ __launch_bounds__(256) void merge_kernel(int* __restrict__ degr,
                                                    int* __restrict__ deg) {
    int i = blockIdx.x * 256 + threadIdx.x;
    if (i >= NN) return;
    int s = 0;
#pragma unroll
    for (int r = 0; r < NREP; r++) {
        int t = degr[r * RSTRIDE + i];
        degr[r * RSTRIDE + i] = s;
        s += t;
    }
    deg[i] = s;
}

// ---------- parallel exclusive scan of deg -> rowptr (3 kernels, full-chip) ----------
__global__ __launch_bounds__(256) void tilesum_kernel(const int* __restrict__ deg,
                                                      int* __restrict__ tilesum) {
    int i = blockIdx.x * 256 + threadIdx.x;
    int v = (i < NN) ? deg[i] : 0;
    __shared__ int s[256];
    s[threadIdx.x] = v;
    __syncthreads();
    for (int off = 128; off > 0; off >>= 1) {
        if (threadIdx.x < off) s[threadIdx.x] += s[threadIdx.x + off];
        __syncthreads();
    }
    if (threadIdx.x == 0) tilesum[blockIdx.x] = s[0];
}

__global__ __launch_bounds__(256) void tilescan_kernel(const int* __restrict__ tilesum,
                                                       int* __restrict__ tileoff,
                                                       int* __restrict__ rowptr) {
    int t = threadIdx.x;
    __shared__ int s[256];
    int v = (t < NT) ? tilesum[t] : 0;
    s[t] = v;
    __syncthreads();
    for (int off = 1; off < 256; off <<= 1) {
        int u = (t >= off) ? s[t - off] : 0;
        __syncthreads();
        s[t] += u;
        __syncthreads();
    }
    if (t < NT) tileoff[t] = s[t] - v;   // exclusive tile offset
    if (t == NT - 1) rowptr[NN] = s[t];  // grand total
}

__global__ __launch_bounds__(256) void rowptr_kernel(const int* __restrict__ deg,
                                                     const int* __restrict__ tileoff,
                                                     int* __restrict__ rowptr) {
    int i = blockIdx.x * 256 + threadIdx.x;
    int t = threadIdx.x;
    int v = (i < NN) ? deg[i] : 0;
    __shared__ int s[256];
    s[t] = v;
    __syncthreads();
    for (int off = 1; off < 256; off <<= 1) {
        int u = (t >= off) ? s[t - off] : 0;
        __syncthreads();
        s[t] += u;
        __syncthreads();
    }
    if (i < NN) rowptr[i] = tileoff[blockIdx.x] + s[t] - v;
}

// atomic-free scatter: col[rowptr[d] + roff[rep][d] + pos[e]] = src[e]
__global__ __launch_bounds__(256) void fill_kernel(const int* __restrict__ src,
                                                   const int* __restrict__ dst,
                                                   const int* __restrict__ pos,
                                                   const int* __restrict__ rowptr,
                                                   const int* __restrict__ roff,
                                                   int* __restrict__ col) {
    int t = blockIdx.x * 256 + threadIdx.x;  // [0, NE/4)
    if (t >= NE / 4) return;
    const int* ro = roff + (blockIdx.x & (NREP - 1)) * RSTRIDE;
    int4 d = ((const int4*)dst)[t];
    int4 p = ((const int4*)pos)[t];
    int4 s = ((const int4*)src)[t];
    col[rowptr[d.x] + ro[d.x] + p.x] = s.x;
    col[rowptr[d.y] + ro[d.y] + p.y] = s.y;
    col[rowptr[d.z] + ro[d.z] + p.z] = s.z;
    col[rowptr[d.w] + ro[d.w] + p.w] = s.w;
}

// ---------- weight prep: fp32 [l][k][n] -> bf16 transposed [l][n][k] ----------
__global__ __launch_bounds__(256) void prep_kernel(const float* __restrict__ Ws1,
                                                   const float* __restrict__ Ws2,
                                                   unsigned short* __restrict__ W1T,
                                                   unsigned short* __restrict__ W2T) {
    int idx = blockIdx.x * 256 + threadIdx.x;  // [0, NL*DD*DD)
    int l = idx >> 14;
    int rem = idx & 16383;
    int k = rem >> 7;
    int n = rem & 127;
    int o = (l << 14) + (n << 7) + k;
    W1T[o] = f2bf(Ws1[idx]);
    W2T[o] = f2bf(Ws2[idx]);
}

// ---------- aggregation: hpre[i] = x[i] + sum_{j in N(i)} x[j], bf16 in/out ----------
// Standalone (NOT fused with MLP): gather is latency-bound and needs a big grid
// for memory-level parallelism — fusing into 782 blocks cost 2.4x fetch rate (R5).
// 32 lanes per node, ushort4 per lane; fp32 accum; x8 edge unroll for MLP.
__global__ __launch_bounds__(256) void agg_kernel(const unsigned short* __restrict__ xbf,
                                                  const int* __restrict__ rowptr,
                                                  const int* __restrict__ col,
                                                  unsigned short* __restrict__ hpre) {
    int g = threadIdx.x >> 5;
    int lane = threadIdx.x & 31;
    int node = blockIdx.x * 8 + g;
    int co = lane * 4;
    float a0, a1, a2, a3;
    {
        ushort4 v = *(const ushort4*)(xbf + (size_t)node * DD + co);
        a0 = bf2f(v.x); a1 = bf2f(v.y); a2 = bf2f(v.z); a3 = bf2f(v.w);
    }
    int s = rowptr[node], e = rowptr[node + 1];
    int i = s;
    for (; i + 8 <= e; i += 8) {
        int j0 = col[i], j1 = col[i + 1], j2 = col[i + 2], j3 = col[i + 3];
        int j4 = col[i + 4], j5 = col[i + 5], j6 = col[i + 6], j7 = col[i + 7];
        ushort4 v0 = *(const ushort4*)(xbf + (size_t)j0 * DD + co);
        ushort4 v1 = *(const ushort4*)(xbf + (size_t)j1 * DD + co);
        ushort4 v2 = *(const ushort4*)(xbf + (size_t)j2 * DD + co);
        ushort4 v3 = *(const ushort4*)(xbf + (size_t)j3 * DD + co);
        ushort4 v4 = *(const ushort4*)(xbf + (size_t)j4 * DD + co);
        ushort4 v5 = *(const ushort4*)(xbf + (size_t)j5 * DD + co);
        ushort4 v6 = *(const ushort4*)(xbf + (size_t)j6 * DD + co);
        ushort4 v7 = *(const ushort4*)(xbf + (size_t)j7 * DD + co);
        a0 += bf2f(v0.x) + bf2f(v1.x) + bf2f(v2.x) + bf2f(v3.x)
            + bf2f(v4.x) + bf2f(v5.x) + bf2f(v6.x) + bf2f(v7.x);
        a1 += bf2f(v0.y) + bf2f(v1.y) + bf2f(v2.y) + bf2f(v3.y)
            + bf2f(v4.y) + bf2f(v5.y) + bf2f(v6.y) + bf2f(v7.y);
        a2 += bf2f(v0.z) + bf2f(v1.z) + bf2f(v2.z) + bf2f(v3.z)
            + bf2f(v4.z) + bf2f(v5.z) + bf2f(v6.z) + bf2f(v7.z);
        a3 += bf2f(v0.w) + bf2f(v1.w) + bf2f(v2.w) + bf2f(v3.w)
            + bf2f(v4.w) + bf2f(v5.w) + bf2f(v6.w) + bf2f(v7.w);
    }
    for (; i < e; i++) {
        int j = col[i];
        ushort4 v = *(const ushort4*)(xbf + (size_t)j * DD + co);
        a0 += bf2f(v.x); a1 += bf2f(v.y); a2 += bf2f(v.z); a3 += bf2f(v.w);
    }
    ushort4 o;
    o.x = f2bf(a0); o.y = f2bf(a1); o.z = f2bf(a2); o.w = f2bf(a3);
    *(ushort4*)(hpre + (size_t)node * DD + co) = o;
}

// ---------- fused MLP: out = relu(A@W1+b1)@W2 + b2 (bf16 in/out, fp32 accum) ----------
// 64 rows/block, 4 waves, wave w owns rows [16w,16w+16); 8 n-tiles per wave.
__global__ __launch_bounds__(256) void mlp_kernel(const unsigned short* __restrict__ A,
                                                  const unsigned short* __restrict__ W1T,
                                                  const float* __restrict__ b1,
                                                  const unsigned short* __restrict__ W2T,
                                                  const float* __restrict__ b2,
                                                  unsigned short* __restrict__ out) {
    __shared__ unsigned short Hs[64][136];  // +8 pad
    int tid = threadIdx.x;
    int w = tid >> 6;
    int lane = tid & 63;
    int quad = lane >> 4;
    int li = lane & 15;
    int row0 = blockIdx.x * 64;
    int arow = row0 + 16 * w + li;
    bool avalid = arow < NN;
    const unsigned short* arp = A + (size_t)arow * DD;

    floatx4 acc[8];
#pragma unroll
    for (int tn = 0; tn < 8; tn++) acc[tn] = (floatx4){0.f, 0.f, 0.f, 0.f};

#pragma unroll
    for (int kk = 0; kk < 4; kk++) {
        int k0 = kk * 32 + quad * 8;
        short8 af = avalid ? *(const short8*)(arp + k0)
                           : (short8){0, 0, 0, 0, 0, 0, 0, 0};
#pragma unroll
        for (int tn = 0; tn < 8; tn++) {
            short8 bf = *(const short8*)(W1T + ((tn * 16 + li) << 7) + k0);
            acc[tn] = __builtin_amdgcn_mfma_f32_16x16x32_bf16(af, bf, acc[tn], 0, 0, 0);
        }
    }
    // epilogue A: relu(acc + b1) -> Hs (bf16, row-major for stage-B A-fragments)
#pragma unroll
    for (int tn = 0; tn < 8; tn++) {
        float bias = b1[tn * 16 + li];
#pragma unroll
        for (int r = 0; r < 4; r++) {
            float v = acc[tn][r] + bias;
            v = fmaxf(v, 0.f);
            Hs[16 * w + quad * 4 + r][tn * 16 + li] = f2bf(v);
        }
    }
    __syncthreads();

#pragma unroll
    for (int tn = 0; tn < 8; tn++) acc[tn] = (floatx4){0.f, 0.f, 0.f, 0.f};
#pragma unroll
    for (int kk = 0; kk < 4; kk++) {
        int k0 = kk * 32 + quad * 8;
        short8 af = *(const short8*)&Hs[16 * w + li][k0];
#pragma unroll
        for (int tn = 0; tn < 8; tn++) {
            short8 bf = *(const short8*)(W2T + ((tn * 16 + li) << 7) + k0);
            acc[tn] = __builtin_amdgcn_mfma_f32_16x16x32_bf16(af, bf, acc[tn], 0, 0, 0);
        }
    }
#pragma unroll
    for (int tn = 0; tn < 8; tn++) {
        float bias = b2[tn * 16 + li];
#pragma unroll
        for (int r = 0; r < 4; r++) {
            int grow = row0 + 16 * w + quad * 4 + r;
            if (grow < NN) out[(size_t)grow * DD + tn * 16 + li] = f2bf(acc[tn][r] + bias);
        }
    }
}

// ---------- global add pool: batch sorted -> per-graph contiguous range ----------
__global__ __launch_bounds__(128) void pool_kernel(const unsigned short* __restrict__ x,
                                                   const int* __restrict__ batch,
                                                   float* __restrict__ out) {
    int g = blockIdx.x;
    int lo = 0, hi = NN;
    while (lo < hi) { int mid = (lo + hi) >> 1; if (batch[mid] < g) lo = mid + 1; else hi = mid; }
    int s = lo;
    hi = NN;
    while (lo < hi) { int mid = (lo + hi) >> 1; if (batch[mid] < g + 1) lo = mid + 1; else hi = mid; }
    int e = lo;
    int d = threadIdx.x;
    float acc = 0.f;
    for (int i = s; i < e; i++) acc += bf2f(x[(size_t)i * DD + d]);
    out[g * DD + d] = acc;
}

extern "C" void kernel_launch(void* const* d_in, const int* in_sizes, int n_in,
                              void* d_out, int out_size, void* d_ws, size_t ws_size,
                              hipStream_t stream) {
    const float* x0 = (const float*)d_in[0];
    const int* edge = (const int*)d_in[1];
    const int* batch = (const int*)d_in[2];
    const float* Ws1 = (const float*)d_in[3];
    const float* bs1 = (const float*)d_in[4];
    const float* Ws2 = (const float*)d_in[5];
    const float* bs2 = (const float*)d_in[6];
    float* out = (float*)d_out;
    const int* src = edge;
    const int* dst = edge + NE;

    char* ws = (char*)d_ws;
    size_t off = 0;
    auto alloc = [&](size_t bytes) {
        void* p = ws + off;
        off += (bytes + 255) & ~(size_t)255;
        return p;
    };
    unsigned short* x0bf = (unsigned short*)alloc((size_t)NN * DD * 2);
    unsigned short* xA = (unsigned short*)alloc((size_t)NN * DD * 2);
    unsigned short* xB = (unsigned short*)alloc((size_t)NN * DD * 2);
    unsigned short* hpre = (unsigned short*)alloc((size_t)NN * DD * 2);
    int* col = (int*)alloc((size_t)NE * 4);
    int* pos = (int*)alloc((size_t)NE * 4);
    int* rowptr = (int*)alloc((size_t)(NN + 1) * 4);
    int* deg = (int*)alloc((size_t)(NN + 1) * 4);
    int* degr = (int*)alloc((size_t)NREP * RSTRIDE * 4);  // counters, then roff in-place
    int* tilesum = (int*)alloc((size_t)NT * 4);
    int* tileoff = (int*)alloc((size_t)NT * 4);
    unsigned short* W1T = (unsigned short*)alloc((size_t)NL * DD * DD * 2);
    unsigned short* W2T = (unsigned short*)alloc((size_t)NL * DD * DD * 2);

    hipMemsetAsync(degr, 0, (size_t)NREP * RSTRIDE * 4, stream);

    cvt_kernel<<<(NN * DD / 4) / 256, 256, 0, stream>>>(x0, x0bf);
    pos_kernel<<<NBE, 256, 0, stream>>>(dst, degr, pos);
    merge_kernel<<<NT, 256, 0, stream>>>(degr, deg);
    tilesum_kernel<<<NT, 256, 0, stream>>>(deg, tilesum);
    tilescan_kernel<<<1, 256, 0, stream>>>(tilesum, tileoff, rowptr);
    rowptr_kernel<<<NT, 256, 0, stream>>>(deg, tileoff, rowptr);
    fill_kernel<<<NBE, 256, 0, stream>>>(src, dst, pos, rowptr, degr, col);
    prep_kernel<<<(NL * DD * DD) / 256, 256, 0, stream>>>(Ws1, Ws2, W1T, W2T);

    const unsigned short* xin = x0bf;
    unsigned short* bufs[2] = {xA, xB};
    for (int l = 0; l < NL; l++) {
        agg_kernel<<<NN / 8, 256, 0, stream>>>(xin, rowptr, col, hpre);
        unsigned short* xout = bufs[l & 1];
        mlp_kernel<<<(NN + 63) / 64, 256, 0, stream>>>(hpre, W1T + l * DD * DD, bs1 + l * DD,
                                                       W2T + l * DD * DD, bs2 + l * DD, xout);
        xin = xout;
    }
    pool_kernel<<<NG, 128, 0, stream>>>(xin, batch, out);
}